// Round 1
// baseline (1499.547 us; speedup 1.0000x reference)
//
#include <hip/hip_runtime.h>
#include <cstdint>

#define H 1024
#define F 2048
#define E_N 8
#define BM 128
#define BK 64

typedef __attribute__((ext_vector_type(8))) short short8v;
typedef __attribute__((ext_vector_type(4))) float float4v;
typedef unsigned short u16;

__device__ __forceinline__ u16 f2bf(float f) {
    uint32_t u = __float_as_uint(f);
    u += 0x7FFFu + ((u >> 16) & 1u);   // round-to-nearest-even
    return (u16)(u >> 16);
}

// ---------------- fp32 -> bf16 weight conversion ----------------
__global__ __launch_bounds__(256) void cvt_kernel(const float* __restrict__ src,
                                                  u16* __restrict__ dst, int n) {
    int i = (blockIdx.x * 256 + threadIdx.x) * 4;
    int stride = gridDim.x * 256 * 4;
    for (; i < n; i += stride) {
        float4 v = *(const float4*)(src + i);
        ushort4 o;
        o.x = f2bf(v.x); o.y = f2bf(v.y); o.z = f2bf(v.z); o.w = f2bf(v.w);
        *(ushort4*)(dst + i) = o;
    }
}

// ---------------- router: logits, softmax-top2, counts ----------------
__global__ __launch_bounds__(256) void router_kernel(const float* __restrict__ x,
                                                     const float* __restrict__ gw,
                                                     int* __restrict__ topi,
                                                     float* __restrict__ topw,
                                                     int* __restrict__ counts, int T) {
    int wave = threadIdx.x >> 6, lane = threadIdx.x & 63;
    int t = blockIdx.x * 4 + wave;
    if (t >= T) return;
    const float4* xr = (const float4*)(x + (size_t)t * H);
    float4 xv[4];
#pragma unroll
    for (int i = 0; i < 4; i++) xv[i] = xr[i * 64 + lane];
    float acc[E_N];
#pragma unroll
    for (int e = 0; e < E_N; e++) {
        const float4* gr = (const float4*)(gw + e * H);
        float s = 0.f;
#pragma unroll
        for (int i = 0; i < 4; i++) {
            float4 g = gr[i * 64 + lane];
            s += xv[i].x * g.x + xv[i].y * g.y + xv[i].z * g.z + xv[i].w * g.w;
        }
        acc[e] = s;
    }
#pragma unroll
    for (int e = 0; e < E_N; e++) {
#pragma unroll
        for (int off = 32; off; off >>= 1) acc[e] += __shfl_xor(acc[e], off, 64);
    }
    if (lane == 0) {
        int i0 = 0;
#pragma unroll
        for (int e = 1; e < E_N; e++) if (acc[e] > acc[i0]) i0 = e;
        int i1 = -1;
#pragma unroll
        for (int e = 0; e < E_N; e++) {
            if (e == i0) continue;
            if (i1 < 0 || acc[e] > acc[i1]) i1 = e;
        }
        float e1 = __expf(acc[i1] - acc[i0]);      // softmax over the two picked logits
        float w0 = 1.f / (1.f + e1);
        float w1 = e1 / (1.f + e1);
        topi[t * 2] = i0; topi[t * 2 + 1] = i1;
        topw[t * 2] = w0; topw[t * 2 + 1] = w1;
        atomicAdd(&counts[i0], 1);
        atomicAdd(&counts[i1], 1);
    }
}

// ---------------- tiny serial scan ----------------
__global__ void scan_kernel(const int* __restrict__ counts, int* __restrict__ offsets,
                            int* __restrict__ cursors, int* __restrict__ tileOff) {
    if (threadIdx.x == 0 && blockIdx.x == 0) {
        int o = 0, to = 0;
        for (int e = 0; e < E_N; e++) {
            offsets[e] = o; cursors[e] = o; tileOff[e] = to;
            o += counts[e];
            to += (counts[e] + BM - 1) / BM;
        }
        offsets[E_N] = o; tileOff[E_N] = to;
    }
}

// ---------------- scatter tokens into expert-grouped slots ----------------
__global__ __launch_bounds__(256) void scatter_kernel(const int* __restrict__ topi,
                                                      const float* __restrict__ topw,
                                                      int* __restrict__ cursors,
                                                      int* __restrict__ perm_tok,
                                                      float* __restrict__ perm_gate, int T) {
    int t = blockIdx.x * 256 + threadIdx.x;
    if (t >= T) return;
#pragma unroll
    for (int k = 0; k < 2; k++) {
        int e = topi[t * 2 + k];
        int pos = atomicAdd(&cursors[e], 1);
        perm_tok[pos] = t;
        perm_gate[pos] = topw[t * 2 + k];
    }
}

// ---------------- stage 1: h = gate * silu(x@w1^T) * (x@w3^T)  (bf16 out) ----------------
__global__ __launch_bounds__(256) void stage1_kernel(
    const float* __restrict__ x, const u16* __restrict__ w1b, const u16* __restrict__ w3b,
    const int* __restrict__ perm_tok, const float* __restrict__ perm_gate,
    const int* __restrict__ offsets, const int* __restrict__ tileOff,
    u16* __restrict__ h, int ffnBase, int fchunk) {
    __shared__ u16 lA[BM * BK];
    __shared__ u16 lB1[64 * BK];
    __shared__ u16 lB3[64 * BK];
    __shared__ int ptokS[BM];
    __shared__ float pgateS[BM];

    int rowTile = blockIdx.x;
    if (rowTile >= tileOff[E_N]) return;
    int e = 0;
    while (e < E_N - 1 && rowTile >= tileOff[e + 1]) e++;
    int rbase = offsets[e] + (rowTile - tileOff[e]) * BM;
    int segEnd = offsets[e + 1];

    int tid = threadIdx.x;
    if (tid < BM) {
        int p = rbase + tid; if (p > segEnd - 1) p = segEnd - 1;
        ptokS[tid] = perm_tok[p];
        pgateS[tid] = perm_gate[p];
    }
    int lane = tid & 63, wave = tid >> 6;
    int mBase = (wave >> 1) * 64, nBaseW = (wave & 1) * 32;
    int lrow = lane & 15, kgrp = lane >> 4;
    int nb = blockIdx.y * 64;  // chunk-local ffn col base
    const u16* w1p = w1b + (size_t)e * F * H + (size_t)(ffnBase + nb) * H;
    const u16* w3p = w3b + (size_t)e * F * H + (size_t)(ffnBase + nb) * H;

    float4v acc1[4][2], acc3[4][2];
#pragma unroll
    for (int a = 0; a < 4; a++)
#pragma unroll
        for (int b = 0; b < 2; b++) { acc1[a][b] = (float4v)(0.f); acc3[a][b] = (float4v)(0.f); }

    for (int kt = 0; kt < H / BK; kt++) {
        __syncthreads();
        // stage A (gather x rows, fp32->bf16, XOR-swizzled LDS)
#pragma unroll
        for (int j = 0; j < 4; j++) {
            int idx = j * 256 + tid;
            int r = idx >> 3, kb = (idx & 7) * 8;
            int tok = ptokS[r];
            const float* src = x + (size_t)tok * H + kt * BK + kb;
            float4 v0 = *(const float4*)src;
            float4 v1 = *(const float4*)(src + 4);
            short8v v;
            v[0] = (short)f2bf(v0.x); v[1] = (short)f2bf(v0.y);
            v[2] = (short)f2bf(v0.z); v[3] = (short)f2bf(v0.w);
            v[4] = (short)f2bf(v1.x); v[5] = (short)f2bf(v1.y);
            v[6] = (short)f2bf(v1.z); v[7] = (short)f2bf(v1.w);
            *(short8v*)&lA[r * BK + (((kb >> 3) ^ (r & 7)) << 3)] = v;
        }
        // stage B1/B3 (already bf16)
#pragma unroll
        for (int j = 0; j < 2; j++) {
            int idx = j * 256 + tid;
            int r = idx >> 3, kb = (idx & 7) * 8;
            int sw = r * BK + (((kb >> 3) ^ (r & 7)) << 3);
            *(short8v*)&lB1[sw] = *(const short8v*)(w1p + (size_t)r * H + kt * BK + kb);
            *(short8v*)&lB3[sw] = *(const short8v*)(w3p + (size_t)r * H + kt * BK + kb);
        }
        __syncthreads();
#pragma unroll
        for (int kk = 0; kk < 2; kk++) {
            int kg = kk * 4 + kgrp;
            short8v aF[4], b1F[2], b3F[2];
#pragma unroll
            for (int fm = 0; fm < 4; fm++) {
                int r = mBase + fm * 16 + lrow;
                aF[fm] = *(const short8v*)&lA[r * BK + ((kg ^ (r & 7)) << 3)];
            }
#pragma unroll
            for (int fn = 0; fn < 2; fn++) {
                int c = nBaseW + fn * 16 + lrow;
                b1F[fn] = *(const short8v*)&lB1[c * BK + ((kg ^ (c & 7)) << 3)];
                b3F[fn] = *(const short8v*)&lB3[c * BK + ((kg ^ (c & 7)) << 3)];
            }
#pragma unroll
            for (int fm = 0; fm < 4; fm++)
#pragma unroll
                for (int fn = 0; fn < 2; fn++) {
                    acc1[fm][fn] = __builtin_amdgcn_mfma_f32_16x16x32_bf16(aF[fm], b1F[fn], acc1[fm][fn], 0, 0, 0);
                    acc3[fm][fn] = __builtin_amdgcn_mfma_f32_16x16x32_bf16(aF[fm], b3F[fn], acc3[fm][fn], 0, 0, 0);
                }
        }
    }
    // epilogue: silu(a1)*a3*gate -> bf16 h
    int rif = (lane >> 4) * 4;
#pragma unroll
    for (int fm = 0; fm < 4; fm++) {
#pragma unroll
        for (int reg = 0; reg < 4; reg++) {
            int rowIdx = mBase + fm * 16 + rif + reg;
            int p = rbase + rowIdx;
            if (p < segEnd) {
                float g = pgateS[rowIdx];
#pragma unroll
                for (int fn = 0; fn < 2; fn++) {
                    float a1 = acc1[fm][fn][reg], a3 = acc3[fm][fn][reg];
                    float sv = a1 / (1.f + __expf(-a1));
                    float hv = sv * a3 * g;
                    int ncol = nb + nBaseW + fn * 16 + (lane & 15);
                    h[(size_t)p * fchunk + ncol] = f2bf(hv);
                }
            }
        }
    }
}

// ---------------- stage 2: out[tok] += h @ w2^T (atomic combine) ----------------
__global__ __launch_bounds__(256) void stage2_kernel(
    const u16* __restrict__ h, const u16* __restrict__ w2b,
    const int* __restrict__ perm_tok,
    const int* __restrict__ offsets, const int* __restrict__ tileOff,
    float* __restrict__ out, int ffnBase, int fchunk) {
    __shared__ u16 lA[BM * BK];
    __shared__ u16 lB[BM * BK];
    __shared__ int ptokS[BM];

    int rowTile = blockIdx.x;
    if (rowTile >= tileOff[E_N]) return;
    int e = 0;
    while (e < E_N - 1 && rowTile >= tileOff[e + 1]) e++;
    int rbase = offsets[e] + (rowTile - tileOff[e]) * BM;
    int segEnd = offsets[e + 1];

    int tid = threadIdx.x;
    if (tid < BM) {
        int p = rbase + tid; if (p > segEnd - 1) p = segEnd - 1;
        ptokS[tid] = perm_tok[p];
    }
    int lane = tid & 63, wave = tid >> 6;
    int mBase = (wave >> 1) * 64, nBaseW = (wave & 1) * 64;
    int lrow = lane & 15, kgrp = lane >> 4;
    int nb = blockIdx.y * 128;  // output col base (H dim)
    const u16* w2p = w2b + (size_t)e * H * F + (size_t)nb * F + ffnBase;

    float4v acc[4][4];
#pragma unroll
    for (int a = 0; a < 4; a++)
#pragma unroll
        for (int b = 0; b < 4; b++) acc[a][b] = (float4v)(0.f);

    for (int kt = 0; kt < fchunk / BK; kt++) {
        __syncthreads();
#pragma unroll
        for (int j = 0; j < 4; j++) {
            int idx = j * 256 + tid;
            int r = idx >> 3, kb = (idx & 7) * 8;
            int pr = rbase + r; if (pr > segEnd - 1) pr = segEnd - 1;
            *(short8v*)&lA[r * BK + (((kb >> 3) ^ (r & 7)) << 3)] =
                *(const short8v*)(h + (size_t)pr * fchunk + kt * BK + kb);
        }
#pragma unroll
        for (int j = 0; j < 4; j++) {
            int idx = j * 256 + tid;
            int r = idx >> 3, kb = (idx & 7) * 8;
            *(short8v*)&lB[r * BK + (((kb >> 3) ^ (r & 7)) << 3)] =
                *(const short8v*)(w2p + (size_t)r * F + kt * BK + kb);
        }
        __syncthreads();
#pragma unroll
        for (int kk = 0; kk < 2; kk++) {
            int kg = kk * 4 + kgrp;
            short8v aF[4], bF[4];
#pragma unroll
            for (int fm = 0; fm < 4; fm++) {
                int r = mBase + fm * 16 + lrow;
                aF[fm] = *(const short8v*)&lA[r * BK + ((kg ^ (r & 7)) << 3)];
            }
#pragma unroll
            for (int fn = 0; fn < 4; fn++) {
                int c = nBaseW + fn * 16 + lrow;
                bF[fn] = *(const short8v*)&lB[c * BK + ((kg ^ (c & 7)) << 3)];
            }
#pragma unroll
            for (int fm = 0; fm < 4; fm++)
#pragma unroll
                for (int fn = 0; fn < 4; fn++)
                    acc[fm][fn] = __builtin_amdgcn_mfma_f32_16x16x32_bf16(aF[fm], bF[fn], acc[fm][fn], 0, 0, 0);
        }
    }
    int rif = (lane >> 4) * 4;
#pragma unroll
    for (int fm = 0; fm < 4; fm++) {
#pragma unroll
        for (int reg = 0; reg < 4; reg++) {
            int rowIdx = mBase + fm * 16 + rif + reg;
            int p = rbase + rowIdx;
            if (p < segEnd) {
                int t = ptokS[rowIdx];
#pragma unroll
                for (int fn = 0; fn < 4; fn++) {
                    int n = nb + nBaseW + fn * 16 + (lane & 15);
                    atomicAdd(&out[(size_t)t * H + n], acc[fm][fn][reg]);
                }
            }
        }
    }
}

extern "C" void kernel_launch(void* const* d_in, const int* in_sizes, int n_in,
                              void* d_out, int out_size, void* d_ws, size_t ws_size,
                              hipStream_t stream) {
    (void)n_in;
    const float* x  = (const float*)d_in[0];
    const float* gw = (const float*)d_in[1];
    const float* w1 = (const float*)d_in[2];
    const float* w2 = (const float*)d_in[3];
    const float* w3 = (const float*)d_in[4];
    float* out = (float*)d_out;
    int T = in_sizes[0] / H;   // 16384
    int P = T * 2;

    char* ws = (char*)d_ws;
    size_t off = 0;
    auto alloc = [&](size_t b) { size_t c = off; off = (off + b + 255) & ~(size_t)255; return c; };
    size_t misc_o  = alloc(256);
    int* counts  = (int*)(ws + misc_o);
    int* offsets = (int*)(ws + misc_o + 64);
    int* cursors = (int*)(ws + misc_o + 128);
    int* tileOff = (int*)(ws + misc_o + 192);
    size_t topi_o  = alloc((size_t)T * 2 * 4);
    size_t topw_o  = alloc((size_t)T * 2 * 4);
    size_t ptok_o  = alloc((size_t)P * 4);
    size_t pgate_o = alloc((size_t)P * 4);
    size_t w1b_o = alloc((size_t)E_N * F * H * 2);
    size_t w3b_o = alloc((size_t)E_N * F * H * 2);
    size_t w2b_o = alloc((size_t)E_N * H * F * 2);
    // pick largest FFN chunk whose h buffer fits in the remaining workspace
    int fchunk = 2048;
    while (fchunk > 256 && off + (size_t)P * fchunk * 2 > ws_size) fchunk >>= 1;
    size_t h_o = alloc((size_t)P * fchunk * 2);

    hipMemsetAsync(ws + misc_o, 0, 256, stream);
    hipMemsetAsync(d_out, 0, (size_t)out_size * 4, stream);

    int nW = E_N * F * H;
    cvt_kernel<<<4096, 256, 0, stream>>>(w1, (u16*)(ws + w1b_o), nW);
    cvt_kernel<<<4096, 256, 0, stream>>>(w3, (u16*)(ws + w3b_o), nW);
    cvt_kernel<<<4096, 256, 0, stream>>>(w2, (u16*)(ws + w2b_o), nW);

    router_kernel<<<T / 4, 256, 0, stream>>>(x, gw, (int*)(ws + topi_o), (float*)(ws + topw_o), counts, T);
    scan_kernel<<<1, 64, 0, stream>>>(counts, offsets, cursors, tileOff);
    scatter_kernel<<<T / 256, 256, 0, stream>>>((int*)(ws + topi_o), (float*)(ws + topw_o),
                                                cursors, (int*)(ws + ptok_o), (float*)(ws + pgate_o), T);

    int maxTiles = P / BM + E_N;
    int nchunk = F / fchunk;
    for (int c = 0; c < nchunk; c++) {
        dim3 g1(maxTiles, fchunk / 64);
        stage1_kernel<<<g1, 256, 0, stream>>>(x, (u16*)(ws + w1b_o), (u16*)(ws + w3b_o),
                                              (int*)(ws + ptok_o), (float*)(ws + pgate_o),
                                              offsets, tileOff, (u16*)(ws + h_o), c * fchunk, fchunk);
        dim3 g2(maxTiles, H / 128);
        stage2_kernel<<<g2, 256, 0, stream>>>((u16*)(ws + h_o), (u16*)(ws + w2b_o),
                                              (int*)(ws + ptok_o), offsets, tileOff,
                                              out, c * fchunk, fchunk);
    }
}

// Round 3
// 1225.817 us; speedup vs baseline: 1.2233x; 1.2233x over previous
//
#include <hip/hip_runtime.h>
#include <cstdint>

#define H 1024
#define F 2048
#define E_N 8
#define BM 128
#define BK 64

typedef __attribute__((ext_vector_type(8))) short short8v;
typedef __attribute__((ext_vector_type(4))) float float4v;
typedef unsigned short u16;

__device__ __forceinline__ u16 f2bf(float f) {
    uint32_t u = __float_as_uint(f);
    u += 0x7FFFu + ((u >> 16) & 1u);   // round-to-nearest-even
    return (u16)(u >> 16);
}
__device__ __forceinline__ float bf2f(u16 b) {
    return __uint_as_float(((uint32_t)b) << 16);
}

__device__ __forceinline__ void gload16(const void* g, void* l) {
    __builtin_amdgcn_global_load_lds((const __attribute__((address_space(1))) uint32_t*)g,
                                     (__attribute__((address_space(3))) uint32_t*)l, 16, 0, 0);
}

// bijective XCD chunk swizzle (m204) + tile-mid / gy-inner order
__device__ __forceinline__ void decode_swz(int bid, int nTiles, int ngy, int gyc,
                                           int& tile, int& gy) {
    int nblk = nTiles * ngy;
    int q = nblk >> 3, r = nblk & 7;
    int xcd = bid & 7, pos = bid >> 3;
    int cid = (xcd < r ? xcd * (q + 1) : r * (q + 1) + (xcd - r) * q) + pos;
    int per = nTiles * gyc;
    int chunk = cid / per, rem = cid - chunk * per;
    tile = rem / gyc;
    gy = chunk * gyc + (rem - (rem / gyc) * gyc);
}

// ---------------- fp32 -> bf16 (weights and x) ----------------
__global__ __launch_bounds__(256) void cvt_kernel(const float* __restrict__ src,
                                                  u16* __restrict__ dst, int n) {
    int i = (blockIdx.x * 256 + threadIdx.x) * 4;
    int stride = gridDim.x * 256 * 4;
    for (; i < n; i += stride) {
        float4 v = *(const float4*)(src + i);
        ushort4 o;
        o.x = f2bf(v.x); o.y = f2bf(v.y); o.z = f2bf(v.z); o.w = f2bf(v.w);
        *(ushort4*)(dst + i) = o;
    }
}

// ---------------- router ----------------
__global__ __launch_bounds__(256) void router_kernel(const float* __restrict__ x,
                                                     const float* __restrict__ gw,
                                                     int* __restrict__ topi,
                                                     float* __restrict__ topw,
                                                     int* __restrict__ counts, int T) {
    int wave = threadIdx.x >> 6, lane = threadIdx.x & 63;
    int t = blockIdx.x * 4 + wave;
    if (t >= T) return;
    const float4* xr = (const float4*)(x + (size_t)t * H);
    float4 xv[4];
#pragma unroll
    for (int i = 0; i < 4; i++) xv[i] = xr[i * 64 + lane];
    float acc[E_N];
#pragma unroll
    for (int e = 0; e < E_N; e++) {
        const float4* gr = (const float4*)(gw + e * H);
        float s = 0.f;
#pragma unroll
        for (int i = 0; i < 4; i++) {
            float4 g = gr[i * 64 + lane];
            s += xv[i].x * g.x + xv[i].y * g.y + xv[i].z * g.z + xv[i].w * g.w;
        }
        acc[e] = s;
    }
#pragma unroll
    for (int e = 0; e < E_N; e++) {
#pragma unroll
        for (int off = 32; off; off >>= 1) acc[e] += __shfl_xor(acc[e], off, 64);
    }
    if (lane == 0) {
        int i0 = 0;
#pragma unroll
        for (int e = 1; e < E_N; e++) if (acc[e] > acc[i0]) i0 = e;
        int i1 = -1;
#pragma unroll
        for (int e = 0; e < E_N; e++) {
            if (e == i0) continue;
            if (i1 < 0 || acc[e] > acc[i1]) i1 = e;
        }
        float e1 = __expf(acc[i1] - acc[i0]);
        float w0 = 1.f / (1.f + e1);
        float w1v = e1 / (1.f + e1);
        topi[t * 2] = i0; topi[t * 2 + 1] = i1;
        topw[t * 2] = w0; topw[t * 2 + 1] = w1v;
        atomicAdd(&counts[i0], 1);
        atomicAdd(&counts[i1], 1);
    }
}

// ---------------- tiny serial scan ----------------
__global__ void scan_kernel(const int* __restrict__ counts, int* __restrict__ offsets,
                            int* __restrict__ cursors, int* __restrict__ tileOff) {
    if (threadIdx.x == 0 && blockIdx.x == 0) {
        int o = 0, to = 0;
        for (int e = 0; e < E_N; e++) {
            offsets[e] = o; cursors[e] = o; tileOff[e] = to;
            o += counts[e];
            to += (counts[e] + BM - 1) / BM;
        }
        offsets[E_N] = o; tileOff[E_N] = to;
    }
}

// ---------------- scatter: slots + inverse map ----------------
__global__ __launch_bounds__(256) void scatter_kernel(const int* __restrict__ topi,
                                                      const float* __restrict__ topw,
                                                      int* __restrict__ cursors,
                                                      int* __restrict__ perm_tok,
                                                      float* __restrict__ perm_gate,
                                                      int* __restrict__ inv, int T) {
    int t = blockIdx.x * 256 + threadIdx.x;
    if (t >= T) return;
#pragma unroll
    for (int k = 0; k < 2; k++) {
        int e = topi[t * 2 + k];
        int pos = atomicAdd(&cursors[e], 1);
        perm_tok[pos] = t;
        perm_gate[pos] = topw[t * 2 + k];
        inv[t * 2 + k] = pos;
    }
}

// ---------------- stage 1: h = gate * silu(xg@w1^T) * (xg@w3^T) ----------------
__global__ __launch_bounds__(256) void stage1_kernel(
    const u16* __restrict__ xg, const u16* __restrict__ w1b, const u16* __restrict__ w3b,
    const int* __restrict__ perm_tok, const float* __restrict__ perm_gate,
    const int* __restrict__ offsets, const int* __restrict__ tileOff,
    u16* __restrict__ h, int cstart, int tpcThis) {
    __shared__ u16 lA[BM * BK];
    __shared__ u16 lB1[64 * BK];
    __shared__ u16 lB3[64 * BK];
    __shared__ int ptokS[BM];
    __shared__ float pgateS[BM];

    int tileL, nbIdx;
    decode_swz(blockIdx.x, tpcThis, F / 64, 4, tileL, nbIdx);
    int tile = cstart + tileL;
    if (tile >= tileOff[E_N]) return;
    int e = 0;
    while (e < E_N - 1 && tile >= tileOff[e + 1]) e++;
    int rbase = offsets[e] + (tile - tileOff[e]) * BM;
    int segEnd = offsets[e + 1];
    int e0 = 0;
    while (e0 < E_N - 1 && cstart >= tileOff[e0 + 1]) e0++;
    int chunkBase = offsets[e0] + (cstart - tileOff[e0]) * BM;

    int tid = threadIdx.x;
    if (tid < BM) {
        int p = rbase + tid; if (p > segEnd - 1) p = segEnd - 1;
        ptokS[tid] = perm_tok[p];
        pgateS[tid] = perm_gate[p];
    }
    __syncthreads();

    int lane = tid & 63, wave = tid >> 6;
    int mBase = (wave >> 1) * 64, nBaseW = (wave & 1) * 32;
    int lrow = lane & 15, kgrp = lane >> 4;
    int nb = nbIdx * 64;
    const u16* w1p = w1b + (size_t)e * F * H + (size_t)nb * H;
    const u16* w3p = w3b + (size_t)e * F * H + (size_t)nb * H;

    // swizzled-source staging: LDS[r][c8] = G[r][c8 ^ (r&7)] (8-elem units)
    int lr = lane >> 3;
    int csw = ((lane & 7) ^ lr) << 3;

    const u16* aSrc[4];
#pragma unroll
    for (int j = 0; j < 4; j++) {
        int rb = (j * 4 + wave) * 8;
        int tok = ptokS[rb + lr];
        aSrc[j] = xg + (size_t)tok * H + csw;
    }
    const u16 *b1Src[2], *b3Src[2];
#pragma unroll
    for (int j = 0; j < 2; j++) {
        int rr = (j * 4 + wave) * 8 + lr;
        b1Src[j] = w1p + (size_t)rr * H + csw;
        b3Src[j] = w3p + (size_t)rr * H + csw;
    }

    float4v acc1[4][2], acc3[4][2];
#pragma unroll
    for (int a = 0; a < 4; a++)
#pragma unroll
        for (int b = 0; b < 2; b++) { acc1[a][b] = (float4v)(0.f); acc3[a][b] = (float4v)(0.f); }

    for (int kt = 0; kt < H / BK; kt++) {
        int ko = kt * BK;
#pragma unroll
        for (int j = 0; j < 4; j++)
            gload16(aSrc[j] + ko, &lA[((j * 4 + wave) * 8) * BK]);
#pragma unroll
        for (int j = 0; j < 2; j++) {
            int rb = (j * 4 + wave) * 8;
            gload16(b1Src[j] + ko, &lB1[rb * BK]);
            gload16(b3Src[j] + ko, &lB3[rb * BK]);
        }
        __syncthreads();
#pragma unroll
        for (int kk = 0; kk < 2; kk++) {
            int kg = kk * 4 + kgrp;
            short8v aF[4], b1F[2], b3F[2];
#pragma unroll
            for (int fm = 0; fm < 4; fm++) {
                int r = mBase + fm * 16 + lrow;
                aF[fm] = *(const short8v*)&lA[r * BK + ((kg ^ (r & 7)) << 3)];
            }
#pragma unroll
            for (int fn = 0; fn < 2; fn++) {
                int c = nBaseW + fn * 16 + lrow;
                b1F[fn] = *(const short8v*)&lB1[c * BK + ((kg ^ (c & 7)) << 3)];
                b3F[fn] = *(const short8v*)&lB3[c * BK + ((kg ^ (c & 7)) << 3)];
            }
#pragma unroll
            for (int fm = 0; fm < 4; fm++)
#pragma unroll
                for (int fn = 0; fn < 2; fn++) {
                    acc1[fm][fn] = __builtin_amdgcn_mfma_f32_16x16x32_bf16(aF[fm], b1F[fn], acc1[fm][fn], 0, 0, 0);
                    acc3[fm][fn] = __builtin_amdgcn_mfma_f32_16x16x32_bf16(aF[fm], b3F[fn], acc3[fm][fn], 0, 0, 0);
                }
        }
        __syncthreads();
    }
    int rif = (lane >> 4) * 4;
#pragma unroll
    for (int fm = 0; fm < 4; fm++) {
#pragma unroll
        for (int reg = 0; reg < 4; reg++) {
            int rowIdx = mBase + fm * 16 + rif + reg;
            int p = rbase + rowIdx;
            if (p < segEnd) {
                float g = pgateS[rowIdx];
#pragma unroll
                for (int fn = 0; fn < 2; fn++) {
                    float a1 = acc1[fm][fn][reg], a3 = acc3[fm][fn][reg];
                    float sv = a1 / (1.f + __expf(-a1));
                    float hv = sv * a3 * g;
                    int ncol = nb + nBaseW + fn * 16 + (lane & 15);
                    h[(size_t)(p - chunkBase) * F + ncol] = f2bf(hv);
                }
            }
        }
    }
}

// ---------------- stage 2: y[p] = h[p] @ w2^T (bf16 out, written once) ----------------
__global__ __launch_bounds__(256) void stage2_kernel(
    const u16* __restrict__ h, const u16* __restrict__ w2b,
    const int* __restrict__ offsets, const int* __restrict__ tileOff,
    u16* __restrict__ y, int cstart, int tpcThis) {
    __shared__ u16 lA[BM * BK];
    __shared__ u16 lB[BM * BK];

    int tileL, nbIdx;
    decode_swz(blockIdx.x, tpcThis, H / 128, 4, tileL, nbIdx);
    int tile = cstart + tileL;
    if (tile >= tileOff[E_N]) return;
    int e = 0;
    while (e < E_N - 1 && tile >= tileOff[e + 1]) e++;
    int rbase = offsets[e] + (tile - tileOff[e]) * BM;
    int segEnd = offsets[e + 1];
    int e0 = 0;
    while (e0 < E_N - 1 && cstart >= tileOff[e0 + 1]) e0++;
    int chunkBase = offsets[e0] + (cstart - tileOff[e0]) * BM;

    int tid = threadIdx.x;
    int lane = tid & 63, wave = tid >> 6;
    int mBase = (wave >> 1) * 64, nBaseW = (wave & 1) * 64;
    int lrow = lane & 15, kgrp = lane >> 4;
    int nb = nbIdx * 128;
    const u16* w2p = w2b + (size_t)e * H * F + (size_t)nb * F;

    int lr = lane >> 3;
    int csw = ((lane & 7) ^ lr) << 3;

    const u16 *aSrc[4], *bSrc[4];
#pragma unroll
    for (int j = 0; j < 4; j++) {
        int rb = (j * 4 + wave) * 8;
        int p = rbase + rb + lr; if (p > segEnd - 1) p = segEnd - 1;
        aSrc[j] = h + (size_t)(p - chunkBase) * F + csw;
        int rr = rb + lr;
        bSrc[j] = w2p + (size_t)rr * F + csw;
    }

    float4v acc[4][4];
#pragma unroll
    for (int a = 0; a < 4; a++)
#pragma unroll
        for (int b = 0; b < 4; b++) acc[a][b] = (float4v)(0.f);

    for (int kt = 0; kt < F / BK; kt++) {
        int ko = kt * BK;
#pragma unroll
        for (int j = 0; j < 4; j++) {
            int rb = (j * 4 + wave) * 8;
            gload16(aSrc[j] + ko, &lA[rb * BK]);
            gload16(bSrc[j] + ko, &lB[rb * BK]);
        }
        __syncthreads();
#pragma unroll
        for (int kk = 0; kk < 2; kk++) {
            int kg = kk * 4 + kgrp;
            short8v aF[4], bF[4];
#pragma unroll
            for (int fm = 0; fm < 4; fm++) {
                int r = mBase + fm * 16 + lrow;
                aF[fm] = *(const short8v*)&lA[r * BK + ((kg ^ (r & 7)) << 3)];
            }
#pragma unroll
            for (int fn = 0; fn < 4; fn++) {
                int c = nBaseW + fn * 16 + lrow;
                bF[fn] = *(const short8v*)&lB[c * BK + ((kg ^ (c & 7)) << 3)];
            }
#pragma unroll
            for (int fm = 0; fm < 4; fm++)
#pragma unroll
                for (int fn = 0; fn < 4; fn++)
                    acc[fm][fn] = __builtin_amdgcn_mfma_f32_16x16x32_bf16(aF[fm], bF[fn], acc[fm][fn], 0, 0, 0);
        }
        __syncthreads();
    }
    int rif = (lane >> 4) * 4;
#pragma unroll
    for (int fm = 0; fm < 4; fm++) {
#pragma unroll
        for (int reg = 0; reg < 4; reg++) {
            int rowIdx = mBase + fm * 16 + rif + reg;
            int p = rbase + rowIdx;
            if (p < segEnd) {
#pragma unroll
                for (int fn = 0; fn < 4; fn++) {
                    int n = nb + nBaseW + fn * 16 + (lane & 15);
                    y[(size_t)p * H + n] = f2bf(acc[fm][fn][reg]);
                }
            }
        }
    }
}

// ---------------- combine: out[t] = y[slot0] + y[slot1] ----------------
__global__ __launch_bounds__(256) void combine_kernel(const u16* __restrict__ y,
                                                      const int* __restrict__ inv,
                                                      float* __restrict__ out) {
    int t = blockIdx.x, c = threadIdx.x;  // 256 threads x 4 floats = H
    int s0 = inv[t * 2], s1 = inv[t * 2 + 1];
    ushort4 a = *(const ushort4*)(y + (size_t)s0 * H + c * 4);
    ushort4 b = *(const ushort4*)(y + (size_t)s1 * H + c * 4);
    float4 o;
    o.x = bf2f(a.x) + bf2f(b.x);
    o.y = bf2f(a.y) + bf2f(b.y);
    o.z = bf2f(a.z) + bf2f(b.z);
    o.w = bf2f(a.w) + bf2f(b.w);
    *(float4*)(out + (size_t)t * H + c * 4) = o;
}

extern "C" void kernel_launch(void* const* d_in, const int* in_sizes, int n_in,
                              void* d_out, int out_size, void* d_ws, size_t ws_size,
                              hipStream_t stream) {
    (void)n_in; (void)out_size;
    const float* x  = (const float*)d_in[0];
    const float* gw = (const float*)d_in[1];
    const float* w1 = (const float*)d_in[2];
    const float* w2 = (const float*)d_in[3];
    const float* w3 = (const float*)d_in[4];
    float* out = (float*)d_out;
    int T = in_sizes[0] / H;   // 16384
    int P = T * 2;

    char* ws = (char*)d_ws;
    size_t off = 0;
    auto alloc = [&](size_t b) { size_t c = off; off = (off + b + 255) & ~(size_t)255; return c; };
    size_t misc_o  = alloc(256);
    int* counts  = (int*)(ws + misc_o);
    int* offsets = (int*)(ws + misc_o + 64);
    int* cursors = (int*)(ws + misc_o + 128);
    int* tileOff = (int*)(ws + misc_o + 192);
    size_t topi_o  = alloc((size_t)T * 2 * 4);
    size_t topw_o  = alloc((size_t)T * 2 * 4);
    size_t ptok_o  = alloc((size_t)P * 4);
    size_t pgate_o = alloc((size_t)P * 4);
    size_t inv_o   = alloc((size_t)T * 2 * 4);
    size_t w1b_o = alloc((size_t)E_N * F * H * 2);
    size_t w3b_o = alloc((size_t)E_N * F * H * 2);
    size_t w2b_o = alloc((size_t)E_N * H * F * 2);
    size_t xg_o  = alloc((size_t)T * H * 2);     // token-order bf16 x
    size_t y_o   = alloc((size_t)P * H * 2);     // bf16 per-slot output

    // h buffer: sized by the ACTUAL remaining workspace (no overflow possible)
    int maxTiles = P / BM + E_N;  // 264
    size_t perTile = (size_t)BM * F * 2;  // 512 KB
    size_t avail = (ws_size > off + 256) ? (ws_size - off - 256) : 0;
    int tpc = (int)(avail / perTile);
    if (tpc > maxTiles) tpc = maxTiles;
    if (tpc < 8) tpc = 8;  // absolute floor (4 MB); round-1 evidence says ws >= 224 MB so this never binds
    size_t h_o = alloc((size_t)tpc * perTile);

    hipMemsetAsync(ws + misc_o, 0, 256, stream);

    int nW = E_N * F * H;
    cvt_kernel<<<4096, 256, 0, stream>>>(w1, (u16*)(ws + w1b_o), nW);
    cvt_kernel<<<4096, 256, 0, stream>>>(w3, (u16*)(ws + w3b_o), nW);
    cvt_kernel<<<4096, 256, 0, stream>>>(w2, (u16*)(ws + w2b_o), nW);
    cvt_kernel<<<4096, 256, 0, stream>>>(x,  (u16*)(ws + xg_o),  T * H);

    router_kernel<<<T / 4, 256, 0, stream>>>(x, gw, (int*)(ws + topi_o), (float*)(ws + topw_o), counts, T);
    scan_kernel<<<1, 64, 0, stream>>>(counts, offsets, cursors, tileOff);
    scatter_kernel<<<T / 256, 256, 0, stream>>>((int*)(ws + topi_o), (float*)(ws + topw_o),
                                                cursors, (int*)(ws + ptok_o), (float*)(ws + pgate_o),
                                                (int*)(ws + inv_o), T);

    for (int cstart = 0; cstart < maxTiles; cstart += tpc) {
        int tpcThis = maxTiles - cstart; if (tpcThis > tpc) tpcThis = tpc;
        stage1_kernel<<<tpcThis * (F / 64), 256, 0, stream>>>(
            (u16*)(ws + xg_o), (u16*)(ws + w1b_o), (u16*)(ws + w3b_o),
            (int*)(ws + ptok_o), (float*)(ws + pgate_o), offsets, tileOff,
            (u16*)(ws + h_o), cstart, tpcThis);
        stage2_kernel<<<tpcThis * (H / 128), 256, 0, stream>>>(
            (u16*)(ws + h_o), (u16*)(ws + w2b_o), offsets, tileOff,
            (u16*)(ws + y_o), cstart, tpcThis);
    }
    combine_kernel<<<T, 256, 0, stream>>>((u16*)(ws + y_o), (int*)(ws + inv_o), out);
}

// Round 4
// 752.647 us; speedup vs baseline: 1.9924x; 1.6287x over previous
//
#include <hip/hip_runtime.h>
#include <cstdint>

#define H 1024
#define F 2048
#define E_N 8
#define BM 128
#define BK 64

typedef __attribute__((ext_vector_type(8))) short short8v;
typedef __attribute__((ext_vector_type(4))) float float4v;
typedef unsigned short u16;

__device__ __forceinline__ u16 f2bf(float f) {
    uint32_t u = __float_as_uint(f);
    u += 0x7FFFu + ((u >> 16) & 1u);   // round-to-nearest-even
    return (u16)(u >> 16);
}
__device__ __forceinline__ float bf2f(u16 b) {
    return __uint_as_float(((uint32_t)b) << 16);
}

__device__ __forceinline__ void gload16(const void* g, void* l) {
    __builtin_amdgcn_global_load_lds((const __attribute__((address_space(1))) uint32_t*)g,
                                     (__attribute__((address_space(3))) uint32_t*)l, 16, 0, 0);
}

// bijective XCD chunk swizzle (m204) + tile-mid / gy-inner order
__device__ __forceinline__ void decode_swz(int bid, int nTiles, int ngy, int gyc,
                                           int& tile, int& gy) {
    int nblk = nTiles * ngy;
    int q = nblk >> 3, r = nblk & 7;
    int xcd = bid & 7, pos = bid >> 3;
    int cid = (xcd < r ? xcd * (q + 1) : r * (q + 1) + (xcd - r) * q) + pos;
    int per = nTiles * gyc;
    int chunk = cid / per, rem = cid - chunk * per;
    tile = rem / gyc;
    gy = chunk * gyc + (rem - (rem / gyc) * gyc);
}

// ---------------- fp32 -> bf16 (weights and x) ----------------
__global__ __launch_bounds__(256) void cvt_kernel(const float* __restrict__ src,
                                                  u16* __restrict__ dst, int n) {
    int i = (blockIdx.x * 256 + threadIdx.x) * 4;
    int stride = gridDim.x * 256 * 4;
    for (; i < n; i += stride) {
        float4 v = *(const float4*)(src + i);
        ushort4 o;
        o.x = f2bf(v.x); o.y = f2bf(v.y); o.z = f2bf(v.z); o.w = f2bf(v.w);
        *(ushort4*)(dst + i) = o;
    }
}

// ---------------- router (no atomics) ----------------
__global__ __launch_bounds__(256) void router_kernel(const float* __restrict__ x,
                                                     const float* __restrict__ gw,
                                                     int* __restrict__ topi,
                                                     float* __restrict__ topw, int T) {
    int wave = threadIdx.x >> 6, lane = threadIdx.x & 63;
    int t = blockIdx.x * 4 + wave;
    if (t >= T) return;
    const float4* xr = (const float4*)(x + (size_t)t * H);
    float4 xv[4];
#pragma unroll
    for (int i = 0; i < 4; i++) xv[i] = xr[i * 64 + lane];
    float acc[E_N];
#pragma unroll
    for (int e = 0; e < E_N; e++) {
        const float4* gr = (const float4*)(gw + e * H);
        float s = 0.f;
#pragma unroll
        for (int i = 0; i < 4; i++) {
            float4 g = gr[i * 64 + lane];
            s += xv[i].x * g.x + xv[i].y * g.y + xv[i].z * g.z + xv[i].w * g.w;
        }
        acc[e] = s;
    }
#pragma unroll
    for (int e = 0; e < E_N; e++) {
#pragma unroll
        for (int off = 32; off; off >>= 1) acc[e] += __shfl_xor(acc[e], off, 64);
    }
    if (lane == 0) {
        int i0 = 0;
#pragma unroll
        for (int e = 1; e < E_N; e++) if (acc[e] > acc[i0]) i0 = e;
        int i1 = -1;
#pragma unroll
        for (int e = 0; e < E_N; e++) {
            if (e == i0) continue;
            if (i1 < 0 || acc[e] > acc[i1]) i1 = e;
        }
        float e1 = __expf(acc[i1] - acc[i0]);
        float w0 = 1.f / (1.f + e1);
        float w1v = e1 / (1.f + e1);
        topi[t * 2] = i0; topi[t * 2 + 1] = i1;
        topw[t * 2] = w0; topw[t * 2 + 1] = w1v;
    }
}

// ---------------- histogram: 8 global atomics per block ----------------
__global__ __launch_bounds__(256) void hist_kernel(const int* __restrict__ topi,
                                                   int* __restrict__ counts, int n) {
    __shared__ int hc[E_N];
    if (threadIdx.x < E_N) hc[threadIdx.x] = 0;
    __syncthreads();
    for (int i = blockIdx.x * 256 + threadIdx.x; i < n; i += gridDim.x * 256)
        atomicAdd(&hc[topi[i]], 1);
    __syncthreads();
    if (threadIdx.x < E_N) atomicAdd(&counts[threadIdx.x], hc[threadIdx.x]);
}

// ---------------- tiny serial scan ----------------
__global__ void scan_kernel(const int* __restrict__ counts, int* __restrict__ offsets,
                            int* __restrict__ cursors, int* __restrict__ tileOff) {
    if (threadIdx.x == 0 && blockIdx.x == 0) {
        int o = 0, to = 0;
        for (int e = 0; e < E_N; e++) {
            offsets[e] = o; cursors[e] = o; tileOff[e] = to;
            o += counts[e];
            to += (counts[e] + BM - 1) / BM;
        }
        offsets[E_N] = o; tileOff[E_N] = to;
    }
}

// ---------------- scatter: block-local ranks, 8 global atomics per block ----------------
__global__ __launch_bounds__(1024) void scatter_kernel(const int* __restrict__ topi,
                                                       const float* __restrict__ topw,
                                                       int* __restrict__ cursors,
                                                       int* __restrict__ perm_tok,
                                                       float* __restrict__ perm_gate,
                                                       int* __restrict__ inv, int n) {
    __shared__ int hc[E_N];
    __shared__ int base[E_N];
    int tid = threadIdx.x;
    if (tid < E_N) hc[tid] = 0;
    __syncthreads();
    int i = blockIdx.x * 1024 + tid;
    int e = 0, lrank = 0;
    bool ok = (i < n);
    if (ok) {
        e = topi[i];
        lrank = atomicAdd(&hc[e], 1);
    }
    __syncthreads();
    if (tid < E_N) base[tid] = atomicAdd(&cursors[tid], hc[tid]);
    __syncthreads();
    if (ok) {
        int pos = base[e] + lrank;
        perm_tok[pos] = i >> 1;
        perm_gate[pos] = topw[i];
        inv[i] = pos;
    }
}

// ---------------- stage 1: h = gate * silu(xg@w1^T) * (xg@w3^T) ----------------
__global__ __launch_bounds__(256) void stage1_kernel(
    const u16* __restrict__ xg, const u16* __restrict__ w1b, const u16* __restrict__ w3b,
    const int* __restrict__ perm_tok, const float* __restrict__ perm_gate,
    const int* __restrict__ offsets, const int* __restrict__ tileOff,
    u16* __restrict__ h, int cstart, int tpcThis) {
    __shared__ u16 lA[BM * BK];
    __shared__ u16 lB1[64 * BK];
    __shared__ u16 lB3[64 * BK];
    __shared__ int ptokS[BM];
    __shared__ float pgateS[BM];

    int tileL, nbIdx;
    decode_swz(blockIdx.x, tpcThis, F / 64, 4, tileL, nbIdx);
    int tile = cstart + tileL;
    if (tile >= tileOff[E_N]) return;
    int e = 0;
    while (e < E_N - 1 && tile >= tileOff[e + 1]) e++;
    int rbase = offsets[e] + (tile - tileOff[e]) * BM;
    int segEnd = offsets[e + 1];
    int e0 = 0;
    while (e0 < E_N - 1 && cstart >= tileOff[e0 + 1]) e0++;
    int chunkBase = offsets[e0] + (cstart - tileOff[e0]) * BM;

    int tid = threadIdx.x;
    if (tid < BM) {
        int p = rbase + tid; if (p > segEnd - 1) p = segEnd - 1;
        ptokS[tid] = perm_tok[p];
        pgateS[tid] = perm_gate[p];
    }
    __syncthreads();

    int lane = tid & 63, wave = tid >> 6;
    int mBase = (wave >> 1) * 64, nBaseW = (wave & 1) * 32;
    int lrow = lane & 15, kgrp = lane >> 4;
    int nb = nbIdx * 64;
    const u16* w1p = w1b + (size_t)e * F * H + (size_t)nb * H;
    const u16* w3p = w3b + (size_t)e * F * H + (size_t)nb * H;

    // swizzled-source staging: LDS[r][c8] = G[r][c8 ^ (r&7)] (8-elem units)
    int lr = lane >> 3;
    int csw = ((lane & 7) ^ lr) << 3;

    const u16* aSrc[4];
#pragma unroll
    for (int j = 0; j < 4; j++) {
        int rb = (j * 4 + wave) * 8;
        int tok = ptokS[rb + lr];
        aSrc[j] = xg + (size_t)tok * H + csw;
    }
    const u16 *b1Src[2], *b3Src[2];
#pragma unroll
    for (int j = 0; j < 2; j++) {
        int rr = (j * 4 + wave) * 8 + lr;
        b1Src[j] = w1p + (size_t)rr * H + csw;
        b3Src[j] = w3p + (size_t)rr * H + csw;
    }

    float4v acc1[4][2], acc3[4][2];
#pragma unroll
    for (int a = 0; a < 4; a++)
#pragma unroll
        for (int b = 0; b < 2; b++) { acc1[a][b] = (float4v)(0.f); acc3[a][b] = (float4v)(0.f); }

    for (int kt = 0; kt < H / BK; kt++) {
        int ko = kt * BK;
#pragma unroll
        for (int j = 0; j < 4; j++)
            gload16(aSrc[j] + ko, &lA[((j * 4 + wave) * 8) * BK]);
#pragma unroll
        for (int j = 0; j < 2; j++) {
            int rb = (j * 4 + wave) * 8;
            gload16(b1Src[j] + ko, &lB1[rb * BK]);
            gload16(b3Src[j] + ko, &lB3[rb * BK]);
        }
        __syncthreads();
#pragma unroll
        for (int kk = 0; kk < 2; kk++) {
            int kg = kk * 4 + kgrp;
            short8v aF[4], b1F[2], b3F[2];
#pragma unroll
            for (int fm = 0; fm < 4; fm++) {
                int r = mBase + fm * 16 + lrow;
                aF[fm] = *(const short8v*)&lA[r * BK + ((kg ^ (r & 7)) << 3)];
            }
#pragma unroll
            for (int fn = 0; fn < 2; fn++) {
                int c = nBaseW + fn * 16 + lrow;
                b1F[fn] = *(const short8v*)&lB1[c * BK + ((kg ^ (c & 7)) << 3)];
                b3F[fn] = *(const short8v*)&lB3[c * BK + ((kg ^ (c & 7)) << 3)];
            }
#pragma unroll
            for (int fm = 0; fm < 4; fm++)
#pragma unroll
                for (int fn = 0; fn < 2; fn++) {
                    acc1[fm][fn] = __builtin_amdgcn_mfma_f32_16x16x32_bf16(aF[fm], b1F[fn], acc1[fm][fn], 0, 0, 0);
                    acc3[fm][fn] = __builtin_amdgcn_mfma_f32_16x16x32_bf16(aF[fm], b3F[fn], acc3[fm][fn], 0, 0, 0);
                }
        }
        __syncthreads();
    }
    int rif = (lane >> 4) * 4;
#pragma unroll
    for (int fm = 0; fm < 4; fm++) {
#pragma unroll
        for (int reg = 0; reg < 4; reg++) {
            int rowIdx = mBase + fm * 16 + rif + reg;
            int p = rbase + rowIdx;
            if (p < segEnd) {
                float g = pgateS[rowIdx];
#pragma unroll
                for (int fn = 0; fn < 2; fn++) {
                    float a1 = acc1[fm][fn][reg], a3 = acc3[fm][fn][reg];
                    float sv = a1 / (1.f + __expf(-a1));
                    float hv = sv * a3 * g;
                    int ncol = nb + nBaseW + fn * 16 + (lane & 15);
                    h[(size_t)(p - chunkBase) * F + ncol] = f2bf(hv);
                }
            }
        }
    }
}

// ---------------- stage 2: y[p] = h[p] @ w2^T (bf16 out, written once) ----------------
__global__ __launch_bounds__(256) void stage2_kernel(
    const u16* __restrict__ h, const u16* __restrict__ w2b,
    const int* __restrict__ offsets, const int* __restrict__ tileOff,
    u16* __restrict__ y, int cstart, int tpcThis) {
    __shared__ u16 lA[BM * BK];
    __shared__ u16 lB[BM * BK];

    int tileL, nbIdx;
    decode_swz(blockIdx.x, tpcThis, H / 128, 4, tileL, nbIdx);
    int tile = cstart + tileL;
    if (tile >= tileOff[E_N]) return;
    int e = 0;
    while (e < E_N - 1 && tile >= tileOff[e + 1]) e++;
    int rbase = offsets[e] + (tile - tileOff[e]) * BM;
    int segEnd = offsets[e + 1];
    int e0 = 0;
    while (e0 < E_N - 1 && cstart >= tileOff[e0 + 1]) e0++;
    int chunkBase = offsets[e0] + (cstart - tileOff[e0]) * BM;

    int tid = threadIdx.x;
    int lane = tid & 63, wave = tid >> 6;
    int mBase = (wave >> 1) * 64, nBaseW = (wave & 1) * 64;
    int lrow = lane & 15, kgrp = lane >> 4;
    int nb = nbIdx * 128;
    const u16* w2p = w2b + (size_t)e * H * F + (size_t)nb * F;

    int lr = lane >> 3;
    int csw = ((lane & 7) ^ lr) << 3;

    const u16 *aSrc[4], *bSrc[4];
#pragma unroll
    for (int j = 0; j < 4; j++) {
        int rb = (j * 4 + wave) * 8;
        int p = rbase + rb + lr; if (p > segEnd - 1) p = segEnd - 1;
        aSrc[j] = h + (size_t)(p - chunkBase) * F + csw;
        int rr = rb + lr;
        bSrc[j] = w2p + (size_t)rr * F + csw;
    }

    float4v acc[4][4];
#pragma unroll
    for (int a = 0; a < 4; a++)
#pragma unroll
        for (int b = 0; b < 4; b++) acc[a][b] = (float4v)(0.f);

    for (int kt = 0; kt < F / BK; kt++) {
        int ko = kt * BK;
#pragma unroll
        for (int j = 0; j < 4; j++) {
            int rb = (j * 4 + wave) * 8;
            gload16(aSrc[j] + ko, &lA[rb * BK]);
            gload16(bSrc[j] + ko, &lB[rb * BK]);
        }
        __syncthreads();
#pragma unroll
        for (int kk = 0; kk < 2; kk++) {
            int kg = kk * 4 + kgrp;
            short8v aF[4], bF[4];
#pragma unroll
            for (int fm = 0; fm < 4; fm++) {
                int r = mBase + fm * 16 + lrow;
                aF[fm] = *(const short8v*)&lA[r * BK + ((kg ^ (r & 7)) << 3)];
            }
#pragma unroll
            for (int fn = 0; fn < 4; fn++) {
                int c = nBaseW + fn * 16 + lrow;
                bF[fn] = *(const short8v*)&lB[c * BK + ((kg ^ (c & 7)) << 3)];
            }
#pragma unroll
            for (int fm = 0; fm < 4; fm++)
#pragma unroll
                for (int fn = 0; fn < 4; fn++)
                    acc[fm][fn] = __builtin_amdgcn_mfma_f32_16x16x32_bf16(aF[fm], bF[fn], acc[fm][fn], 0, 0, 0);
        }
        __syncthreads();
    }
    int rif = (lane >> 4) * 4;
#pragma unroll
    for (int fm = 0; fm < 4; fm++) {
#pragma unroll
        for (int reg = 0; reg < 4; reg++) {
            int rowIdx = mBase + fm * 16 + rif + reg;
            int p = rbase + rowIdx;
            if (p < segEnd) {
#pragma unroll
                for (int fn = 0; fn < 4; fn++) {
                    int n = nb + nBaseW + fn * 16 + (lane & 15);
                    y[(size_t)p * H + n] = f2bf(acc[fm][fn][reg]);
                }
            }
        }
    }
}

// ---------------- combine: out[t] = y[slot0] + y[slot1] ----------------
__global__ __launch_bounds__(256) void combine_kernel(const u16* __restrict__ y,
                                                      const int* __restrict__ inv,
                                                      float* __restrict__ out) {
    int t = blockIdx.x, c = threadIdx.x;  // 256 threads x 4 floats = H
    int s0 = inv[t * 2], s1 = inv[t * 2 + 1];
    ushort4 a = *(const ushort4*)(y + (size_t)s0 * H + c * 4);
    ushort4 b = *(const ushort4*)(y + (size_t)s1 * H + c * 4);
    float4 o;
    o.x = bf2f(a.x) + bf2f(b.x);
    o.y = bf2f(a.y) + bf2f(b.y);
    o.z = bf2f(a.z) + bf2f(b.z);
    o.w = bf2f(a.w) + bf2f(b.w);
    *(float4*)(out + (size_t)t * H + c * 4) = o;
}

extern "C" void kernel_launch(void* const* d_in, const int* in_sizes, int n_in,
                              void* d_out, int out_size, void* d_ws, size_t ws_size,
                              hipStream_t stream) {
    (void)n_in; (void)out_size;
    const float* x  = (const float*)d_in[0];
    const float* gw = (const float*)d_in[1];
    const float* w1 = (const float*)d_in[2];
    const float* w2 = (const float*)d_in[3];
    const float* w3 = (const float*)d_in[4];
    float* out = (float*)d_out;
    int T = in_sizes[0] / H;   // 16384
    int P = T * 2;

    char* ws = (char*)d_ws;
    size_t off = 0;
    auto alloc = [&](size_t b) { size_t c = off; off = (off + b + 255) & ~(size_t)255; return c; };
    size_t misc_o  = alloc(256);
    int* counts  = (int*)(ws + misc_o);
    int* offsets = (int*)(ws + misc_o + 64);
    int* cursors = (int*)(ws + misc_o + 128);
    int* tileOff = (int*)(ws + misc_o + 192);
    size_t topi_o  = alloc((size_t)T * 2 * 4);
    size_t topw_o  = alloc((size_t)T * 2 * 4);
    size_t ptok_o  = alloc((size_t)P * 4);
    size_t pgate_o = alloc((size_t)P * 4);
    size_t inv_o   = alloc((size_t)T * 2 * 4);
    size_t w1b_o = alloc((size_t)E_N * F * H * 2);
    size_t w3b_o = alloc((size_t)E_N * F * H * 2);
    size_t w2b_o = alloc((size_t)E_N * H * F * 2);
    size_t xg_o  = alloc((size_t)T * H * 2);     // token-order bf16 x
    size_t y_o   = alloc((size_t)P * H * 2);     // bf16 per-slot output

    // h buffer: sized by the ACTUAL remaining workspace (no overflow possible)
    int maxTiles = P / BM + E_N;  // 264
    size_t perTile = (size_t)BM * F * 2;  // 512 KB
    size_t avail = (ws_size > off + 256) ? (ws_size - off - 256) : 0;
    int tpc = (int)(avail / perTile);
    if (tpc > maxTiles) tpc = maxTiles;
    if (tpc < 8) tpc = 8;  // absolute floor (4 MB)
    size_t h_o = alloc((size_t)tpc * perTile);

    hipMemsetAsync(ws + misc_o, 0, 256, stream);

    int nW = E_N * F * H;
    cvt_kernel<<<4096, 256, 0, stream>>>(w1, (u16*)(ws + w1b_o), nW);
    cvt_kernel<<<4096, 256, 0, stream>>>(w3, (u16*)(ws + w3b_o), nW);
    cvt_kernel<<<4096, 256, 0, stream>>>(w2, (u16*)(ws + w2b_o), nW);
    cvt_kernel<<<4096, 256, 0, stream>>>(x,  (u16*)(ws + xg_o),  T * H);

    router_kernel<<<T / 4, 256, 0, stream>>>(x, gw, (int*)(ws + topi_o), (float*)(ws + topw_o), T);
    hist_kernel<<<32, 256, 0, stream>>>((int*)(ws + topi_o), counts, P);
    scan_kernel<<<1, 64, 0, stream>>>(counts, offsets, cursors, tileOff);
    scatter_kernel<<<(P + 1023) / 1024, 1024, 0, stream>>>(
        (int*)(ws + topi_o), (float*)(ws + topw_o), cursors,
        (int*)(ws + ptok_o), (float*)(ws + pgate_o), (int*)(ws + inv_o), P);

    for (int cstart = 0; cstart < maxTiles; cstart += tpc) {
        int tpcThis = maxTiles - cstart; if (tpcThis > tpc) tpcThis = tpc;
        stage1_kernel<<<tpcThis * (F / 64), 256, 0, stream>>>(
            (u16*)(ws + xg_o), (u16*)(ws + w1b_o), (u16*)(ws + w3b_o),
            (int*)(ws + ptok_o), (float*)(ws + pgate_o), offsets, tileOff,
            (u16*)(ws + h_o), cstart, tpcThis);
        stage2_kernel<<<tpcThis * (H / 128), 256, 0, stream>>>(
            (u16*)(ws + h_o), (u16*)(ws + w2b_o), offsets, tileOff,
            (u16*)(ws + y_o), cstart, tpcThis);
    }
    combine_kernel<<<T, 256, 0, stream>>>((u16*)(ws + y_o), (int*)(ws + inv_o), out);
}